// Round 9
// baseline (666.673 us; speedup 1.0000x reference)
//
#include <hip/hip_runtime.h>
#include <hip/hip_bf16.h>
#include <cmath>

#define T_  64
#define B_  256
#define D_  2000
#define TN_ 3000
#define E_  256
#define H_  256
#define A_  128
#define V_  128
#define PS_ 64
#define PE_ 64
#define S_  128
#define G1N_ 1500
#define G1L_ 4
#define G2N_ 1500
#define G2L_ 6
#define M_  (T_ * B_)
#define KF_ (H_ + V_ + PE_)
#define NREG 28   // Whh f16 chunks held in registers (of 32)
#define SK_ 4     // split-K chunks for Xe GEMM

typedef __attribute__((ext_vector_type(8))) short short8_t;
typedef __attribute__((ext_vector_type(4))) float floatx4;
typedef _Float16 __attribute__((ext_vector_type(2))) h2_t;
typedef _Float16 __attribute__((ext_vector_type(8))) h8_t;

static __device__ __forceinline__ float sigmoidf_(float x) {
    return 1.0f / (1.0f + __expf(-x));
}

static __device__ __forceinline__ void bsplit_(float v, __hip_bfloat16& hi, __hip_bfloat16& lo) {
    hi = __float2bfloat16(v);
    lo = __float2bfloat16(v - __bfloat162float(hi));
}

static __device__ __forceinline__ float dot2_(unsigned int w, unsigned int h, float acc) {
    union { unsigned int u; h2_t h; } cw, ch;
    cw.u = w; ch.u = h;
#if __has_builtin(__builtin_amdgcn_fdot2)
    return __builtin_amdgcn_fdot2(cw.h, ch.h, acc, false);
#else
    return acc + (float)cw.h[0] * (float)ch.h[0] + (float)cw.h[1] * (float)ch.h[1];
#endif
}

template<int DT>
static __device__ __forceinline__ floatx4 mfma16_(short8_t a, short8_t b, floatx4 c) {
    if constexpr (DT == 0) {
        return __builtin_amdgcn_mfma_f32_16x16x32_bf16(a, b, c, 0, 0, 0);
    } else {
        union { short8_t s; h8_t h; } ua, ub;
        ua.s = a; ub.s = b;
        return __builtin_amdgcn_mfma_f32_16x16x32_f16(ua.h, ub.h, c, 0, 0, 0);
    }
}

// ---------------------------------------------------------------------------
// Split MFMA GEMM: C = A @ B. DT=0: bf16 planes (NPH=3 -> fp32-grade).
// DT=1: f16 planes, NPH=1 (f16 hi-only, ~2^-12 accurate).
// B given as BT[Npad][K] row-major. M mult 128, K mult 32, Npad = nblk*128.
// EPI 1: sigmoid col<128 else tanh. EPI 2: sigmoid col<128, tanh col<256, none above.
// ---------------------------------------------------------------------------
template<int EPI, bool ACCUM, int OUTMODE, int NPH, int DT>
__global__ __launch_bounds__(256)
void k_mgemm3(const __hip_bfloat16* __restrict__ Ahi, const __hip_bfloat16* __restrict__ Alo,
              const __hip_bfloat16* __restrict__ Bhi, const __hip_bfloat16* __restrict__ Blo,
              const float* __restrict__ bias, float* __restrict__ Cf,
              __hip_bfloat16* __restrict__ Chi, __hip_bfloat16* __restrict__ Clo,
              int K, int Nreal, int nblk)
{
    __shared__ __align__(16) short As[4096];
    __shared__ __align__(16) short Bs[4096];

    const int tid  = threadIdx.x;
    const int lane = tid & 63;
    const int w    = tid >> 6;
    const int wm   = w >> 1, wn = w & 1;
    const int lr   = lane & 15;
    const int lkc  = lane >> 4;

    const int bx = blockIdx.x;
    const int m0 = (bx / nblk) * 128;
    const int n0 = (bx % nblk) * 128;

    const int fa = 2 * w;
    const size_t aoff0 = (size_t)(m0 + fa * 16 + lr) * K + lkc * 8;
    const size_t aoff1 = aoff0 + (size_t)16 * K;
    const size_t boff0 = (size_t)(n0 + fa * 16 + lr) * K + lkc * 8;
    const size_t boff1 = boff0 + (size_t)16 * K;

    floatx4 acc[4][4];
#pragma unroll
    for (int i = 0; i < 4; ++i)
#pragma unroll
        for (int j = 0; j < 4; ++j) acc[i][j] = floatx4{0.f, 0.f, 0.f, 0.f};

#pragma unroll 1
    for (int ph = 0; ph < NPH; ++ph) {
        const __hip_bfloat16* Ap = (ph == 2) ? Alo : Ahi;
        const __hip_bfloat16* Bp = (ph == 1) ? Blo : Bhi;

        short8_t ra0 = *(const short8_t*)(const void*)(Ap + aoff0);
        short8_t ra1 = *(const short8_t*)(const void*)(Ap + aoff1);
        short8_t rb0 = *(const short8_t*)(const void*)(Bp + boff0);
        short8_t rb1 = *(const short8_t*)(const void*)(Bp + boff1);

        for (int k0 = 0; k0 < K; k0 += 32) {
            __syncthreads();
            *(short8_t*)(void*)&As[(fa    ) * 512 + lane * 8] = ra0;
            *(short8_t*)(void*)&As[(fa + 1) * 512 + lane * 8] = ra1;
            *(short8_t*)(void*)&Bs[(fa    ) * 512 + lane * 8] = rb0;
            *(short8_t*)(void*)&Bs[(fa + 1) * 512 + lane * 8] = rb1;
            __syncthreads();

            if (k0 + 32 < K) {
                int kn = k0 + 32;
                ra0 = *(const short8_t*)(const void*)(Ap + aoff0 + kn);
                ra1 = *(const short8_t*)(const void*)(Ap + aoff1 + kn);
                rb0 = *(const short8_t*)(const void*)(Bp + boff0 + kn);
                rb1 = *(const short8_t*)(const void*)(Bp + boff1 + kn);
            }

            short8_t af[4], bf[4];
#pragma unroll
            for (int i = 0; i < 4; ++i)
                af[i] = *(const short8_t*)(const void*)&As[(wm * 4 + i) * 512 + lane * 8];
#pragma unroll
            for (int j = 0; j < 4; ++j)
                bf[j] = *(const short8_t*)(const void*)&Bs[(wn * 4 + j) * 512 + lane * 8];
#pragma unroll
            for (int i = 0; i < 4; ++i)
#pragma unroll
                for (int j = 0; j < 4; ++j)
                    acc[i][j] = mfma16_<DT>(af[i], bf[j], acc[i][j]);
        }
    }

    // C/D layout (m89-verified): col=lane&15, row=(lane>>4)*4+r
#pragma unroll
    for (int i = 0; i < 4; ++i) {
        const int row = m0 + wm * 64 + i * 16 + (lane >> 4) * 4;
#pragma unroll
        for (int j = 0; j < 4; ++j) {
            const int col = n0 + wn * 64 + j * 16 + (lane & 15);
            if (col < Nreal) {
                float bv = bias ? bias[col] : 0.0f;
#pragma unroll
                for (int r = 0; r < 4; ++r) {
                    float v = acc[i][j][r] + bv;
                    if (EPI == 1) v = (col < 128) ? sigmoidf_(v) : tanhf(v);
                    if (EPI == 2) {
                        if (col < 128) v = sigmoidf_(v);
                        else if (col < 256) v = tanhf(v);
                    }
                    size_t o = (size_t)(row + r) * Nreal + col;
                    if (OUTMODE == 0) {
                        if (ACCUM) v += Cf[o];
                        Cf[o] = v;
                    } else {
                        __hip_bfloat16 h, l;
                        bsplit_(v, h, l);
                        Chi[o] = h; Clo[o] = l;
                    }
                }
            }
        }
    }
}

// ---------------------------------------------------------------------------
// Fused Xe GEMM, split-K: grid = SK_ * 256. Chunk kc covers K [kc*512,kc*512+512).
// A = f32 X [16384][2000] read directly, per-tile on-the-fly bf16 hi/lo split in
// LDS, 3 MFMA phases; each chunk writes f32 partial P4[kc][16384][256].
// ---------------------------------------------------------------------------
__global__ __launch_bounds__(256)
void k_mgemmX(const float* __restrict__ A,
              const __hip_bfloat16* __restrict__ Bhi, const __hip_bfloat16* __restrict__ Blo,
              float* __restrict__ P4)
{
    const int KP = 2048, KR = 2000, NN = 256, nblk = 2;
    const int KC = 2048 / SK_;               // 512
    __shared__ __align__(16) short Ah[4096];
    __shared__ __align__(16) short Al[4096];
    __shared__ __align__(16) short Bh[4096];
    __shared__ __align__(16) short Bl[4096];

    const int tid  = threadIdx.x;
    const int lane = tid & 63;
    const int w    = tid >> 6;
    const int wm   = w >> 1, wn = w & 1;
    const int lr   = lane & 15;
    const int lkc  = lane >> 4;

    const int kc = blockIdx.x >> 8;          // k-chunk
    const int bx = blockIdx.x & 255;
    const int m0 = (bx / nblk) * 128;
    const int n0 = (bx % nblk) * 128;
    const int KC0 = kc * KC;
    float* dst = P4 + (size_t)kc * (M_ * 256);

    const int fa = 2 * w;
    const float* arow0 = A + (size_t)(m0 + fa * 16 + lr) * KR;
    const float* arow1 = arow0 + (size_t)16 * KR;
    const size_t boff0 = (size_t)(n0 + fa * 16 + lr) * KP + lkc * 8;
    const size_t boff1 = boff0 + (size_t)16 * KP;

    floatx4 acc[4][4];
#pragma unroll
    for (int i = 0; i < 4; ++i)
#pragma unroll
        for (int j = 0; j < 4; ++j) acc[i][j] = floatx4{0.f, 0.f, 0.f, 0.f};

    float a0v[8], a1v[8];
    short8_t bh0, bh1, bl0, bl1;

#define LOADA8(ROW, KB, DST)                                                  \
    if ((KB) + 7 < KR) {                                                      \
        float4 p_ = *(const float4*)((ROW) + (KB));                           \
        float4 q_ = *(const float4*)((ROW) + (KB) + 4);                       \
        DST[0]=p_.x; DST[1]=p_.y; DST[2]=p_.z; DST[3]=p_.w;                   \
        DST[4]=q_.x; DST[5]=q_.y; DST[6]=q_.z; DST[7]=q_.w;                   \
    } else {                                                                  \
        _Pragma("unroll")                                                     \
        for (int ii = 0; ii < 8; ++ii)                                        \
            DST[ii] = ((KB) + ii < KR) ? (ROW)[(KB) + ii] : 0.0f;             \
    }

    {
        const int kb = KC0 + lkc * 8;
        LOADA8(arow0, kb, a0v)
        LOADA8(arow1, kb, a1v)
        bh0 = *(const short8_t*)(const void*)(Bhi + boff0 + KC0);
        bh1 = *(const short8_t*)(const void*)(Bhi + boff1 + KC0);
        bl0 = *(const short8_t*)(const void*)(Blo + boff0 + KC0);
        bl1 = *(const short8_t*)(const void*)(Blo + boff1 + KC0);
    }

    for (int k0 = KC0; k0 < KC0 + KC; k0 += 32) {
        __syncthreads();
        {
            short h8a[8], l8a[8], h8b[8], l8b[8];
#pragma unroll
            for (int i = 0; i < 8; ++i) {
                __hip_bfloat16 h, l;
                bsplit_(a0v[i], h, l);
                h8a[i] = *(short*)&h; l8a[i] = *(short*)&l;
                bsplit_(a1v[i], h, l);
                h8b[i] = *(short*)&h; l8b[i] = *(short*)&l;
            }
            *(short8_t*)(void*)&Ah[(fa    ) * 512 + lane * 8] = *(short8_t*)h8a;
            *(short8_t*)(void*)&Al[(fa    ) * 512 + lane * 8] = *(short8_t*)l8a;
            *(short8_t*)(void*)&Ah[(fa + 1) * 512 + lane * 8] = *(short8_t*)h8b;
            *(short8_t*)(void*)&Al[(fa + 1) * 512 + lane * 8] = *(short8_t*)l8b;
            *(short8_t*)(void*)&Bh[(fa    ) * 512 + lane * 8] = bh0;
            *(short8_t*)(void*)&Bh[(fa + 1) * 512 + lane * 8] = bh1;
            *(short8_t*)(void*)&Bl[(fa    ) * 512 + lane * 8] = bl0;
            *(short8_t*)(void*)&Bl[(fa + 1) * 512 + lane * 8] = bl1;
        }
        __syncthreads();

        if (k0 + 32 < KC0 + KC) {
            const int kb = k0 + 32 + lkc * 8;
            LOADA8(arow0, kb, a0v)
            LOADA8(arow1, kb, a1v)
            bh0 = *(const short8_t*)(const void*)(Bhi + boff0 + k0 + 32);
            bh1 = *(const short8_t*)(const void*)(Bhi + boff1 + k0 + 32);
            bl0 = *(const short8_t*)(const void*)(Blo + boff0 + k0 + 32);
            bl1 = *(const short8_t*)(const void*)(Blo + boff1 + k0 + 32);
        }

        short8_t afh[4], afl[4], bfh[4], bfl[4];
#pragma unroll
        for (int i = 0; i < 4; ++i) {
            afh[i] = *(const short8_t*)(const void*)&Ah[(wm * 4 + i) * 512 + lane * 8];
            bfh[i] = *(const short8_t*)(const void*)&Bh[(wn * 4 + i) * 512 + lane * 8];
        }
#pragma unroll
        for (int i = 0; i < 4; ++i)
#pragma unroll
            for (int j = 0; j < 4; ++j)
                acc[i][j] = mfma16_<0>(afh[i], bfh[j], acc[i][j]);
#pragma unroll
        for (int j = 0; j < 4; ++j)
            bfl[j] = *(const short8_t*)(const void*)&Bl[(wn * 4 + j) * 512 + lane * 8];
#pragma unroll
        for (int i = 0; i < 4; ++i)
#pragma unroll
            for (int j = 0; j < 4; ++j)
                acc[i][j] = mfma16_<0>(afh[i], bfl[j], acc[i][j]);
#pragma unroll
        for (int i = 0; i < 4; ++i)
            afl[i] = *(const short8_t*)(const void*)&Al[(wm * 4 + i) * 512 + lane * 8];
#pragma unroll
        for (int i = 0; i < 4; ++i)
#pragma unroll
            for (int j = 0; j < 4; ++j)
                acc[i][j] = mfma16_<0>(afl[i], bfh[j], acc[i][j]);
    }
#undef LOADA8

#pragma unroll
    for (int i = 0; i < 4; ++i) {
        const int row = m0 + wm * 64 + i * 16 + (lane >> 4) * 4;
#pragma unroll
        for (int j = 0; j < 4; ++j) {
            const int col = n0 + wn * 64 + j * 16 + (lane & 15);
#pragma unroll
            for (int r = 0; r < 4; ++r)
                dst[(size_t)(row + r) * NN + col] = acc[i][j][r];
        }
    }
}

// reduce SK_ partials -> Xe bf16 planes
__global__ void k_reduceX(const float* __restrict__ P4,
                          __hip_bfloat16* __restrict__ hi, __hip_bfloat16* __restrict__ lo)
{
    int idx = blockIdx.x * blockDim.x + threadIdx.x;
    if (idx >= M_ * 256) return;
    const size_t CH = (size_t)M_ * 256;
    float v = P4[idx];
#pragma unroll
    for (int c = 1; c < SK_; ++c) v += P4[idx + c * CH];
    bsplit_(v, hi[idx], lo[idx]);
}

// ---------------------------------------------------------------------------
// fp32 tiled GEMM (PP = ini_embd @ W2 only)
// ---------------------------------------------------------------------------
template<int BM, int BN, int BK, int TM, int TN>
__global__ __launch_bounds__(256)
void k_gemm(const float* __restrict__ A, const float* __restrict__ B,
            float* __restrict__ C, int M, int N, int K)
{
    __shared__ float As[BK][BM + 4];
    __shared__ float Bs[BK][BN + 4];
    const int tid = threadIdx.y * blockDim.x + threadIdx.x;
    const int m0 = blockIdx.y * BM;
    const int n0 = blockIdx.x * BN;
    float acc[TM][TN];
#pragma unroll
    for (int i = 0; i < TM; ++i)
#pragma unroll
        for (int j = 0; j < TN; ++j) acc[i][j] = 0.0f;
    for (int k0 = 0; k0 < K; k0 += BK) {
#pragma unroll
        for (int i = tid; i < BM * BK; i += 256) {
            int r = i / BK, c = i % BK;
            int m = m0 + r;
            As[c][r] = (m < M) ? A[(size_t)m * K + k0 + c] : 0.0f;
        }
#pragma unroll
        for (int i = tid; i < BK * BN; i += 256) {
            int r = i / BN, c = i % BN;
            Bs[r][c] = B[(size_t)(k0 + r) * N + n0 + c];
        }
        __syncthreads();
#pragma unroll
        for (int kk = 0; kk < BK; ++kk) {
            float a[TM], b[TN];
#pragma unroll
            for (int i = 0; i < TM; ++i) a[i] = As[kk][threadIdx.y * TM + i];
#pragma unroll
            for (int j = 0; j < TN; ++j) b[j] = Bs[kk][threadIdx.x * TN + j];
#pragma unroll
            for (int i = 0; i < TM; ++i)
#pragma unroll
                for (int j = 0; j < TN; ++j) acc[i][j] += a[i] * b[j];
        }
        __syncthreads();
    }
#pragma unroll
    for (int i = 0; i < TM; ++i) {
        int m = m0 + threadIdx.y * TM + i;
        if (m >= M) continue;
#pragma unroll
        for (int j = 0; j < TN; ++j)
            C[(size_t)m * N + n0 + threadIdx.x * TN + j] = acc[i][j];
    }
}

// ---------------------------------------------------------------------------
// Pack / convert / split kernels
// ---------------------------------------------------------------------------
__global__ void k_pack_w2(const float* __restrict__ Wa_w, float* __restrict__ W2)
{
    int idx = blockIdx.x * blockDim.x + threadIdx.x;
    if (idx >= E_ * 2 * A_) return;
    int e = idx / (2 * A_), j = idx % (2 * A_);
    W2[idx] = (j < A_) ? Wa_w[(size_t)e * A_ + j]
                       : Wa_w[(size_t)(E_ + e) * A_ + (j - A_)];
}

// WG[1024][256] split planes: n<128 erase_w[k][n]; n<256 add_w[k][n-128];
// n>=256 Wih[n-256][k].  biasG = [erase_b | add_b | gru_bih]
__global__ void k_wg_split(const float* __restrict__ erase_w, const float* __restrict__ add_w,
                           const float* __restrict__ Wih,
                           const float* __restrict__ erase_b, const float* __restrict__ add_b,
                           const float* __restrict__ bih,
                           __hip_bfloat16* __restrict__ WGhi, __hip_bfloat16* __restrict__ WGlo,
                           float* __restrict__ biasG)
{
    int idx = blockIdx.x * blockDim.x + threadIdx.x;
    if (idx < 1024 * 256) {
        int n = idx >> 8, k = idx & 255;
        float v;
        if (n < 128)      v = erase_w[(size_t)k * V_ + n];
        else if (n < 256) v = add_w[(size_t)k * V_ + (n - 128)];
        else              v = Wih[(size_t)(n - 256) * 256 + k];
        bsplit_(v, WGhi[idx], WGlo[idx]);
    }
    if (idx < 1024)
        biasG[idx] = (idx < 128) ? erase_b[idx]
                   : (idx < 256) ? add_b[idx - 128]
                                 : bih[idx - 256];
}

__global__ void k_tranHT_split(const float* __restrict__ tranH_w,
                               __hip_bfloat16* __restrict__ hi, __hip_bfloat16* __restrict__ lo)
{
    int idx = blockIdx.x * blockDim.x + threadIdx.x;
    if (idx >= 256 * 320) return;
    int n = idx / 320, k = idx % 320;
    bsplit_(tranH_w[(size_t)k * 256 + n], hi[idx], lo[idx]);
}

// out_w transposed -> single f16 plane
__global__ void k_outWT_f16(const float* __restrict__ out_w, _Float16* __restrict__ dst)
{
    int idx = blockIdx.x * blockDim.x + threadIdx.x;
    if (idx >= 2048 * 448) return;
    int n = idx / 448, k = idx % 448;
    float v = (n < D_) ? out_w[(size_t)k * D_ + n] : 0.0f;
    dst[idx] = (_Float16)v;
}

__global__ void k_km_split(const float* __restrict__ ini_embd, const int* __restrict__ KMIds,
                           __hip_bfloat16* __restrict__ hi, __hip_bfloat16* __restrict__ lo)
{
    int idx = blockIdx.x * blockDim.x + threadIdx.x;
    if (idx >= S_ * E_) return;
    int s = idx / E_, k = idx % E_;
    bsplit_(ini_embd[(size_t)KMIds[s] * E_ + k], hi[idx], lo[idx]);
}

// embMT full: dst[e][d] = bf16 split of embG[mapInfo[d]][e], d<2000 else 0
__global__ void k_embMT(const float* __restrict__ embG, const int* __restrict__ mapInfo,
                        __hip_bfloat16* __restrict__ hi, __hip_bfloat16* __restrict__ lo)
{
    int idx = blockIdx.x * blockDim.x + threadIdx.x;
    if (idx >= 256 * 2048) return;
    int e = idx >> 11, d = idx & 2047;
    float v = (d < D_) ? embG[(size_t)mapInfo[d] * E_ + e] : 0.0f;
    bsplit_(v, hi[idx], lo[idx]);
}

// Whh[j][e] f32 -> f16 pairs. e2 < 4*NREG -> Wrg[e2][768]; else Wst chunks
__global__ void k_wgru_pack(const float* __restrict__ Whh,
                            unsigned int* __restrict__ Wrg, unsigned int* __restrict__ Wst)
{
    int idx = blockIdx.x * blockDim.x + threadIdx.x;
    if (idx >= 768 * 128) return;
    int j = idx / 128, e2 = idx % 128;
    union { unsigned int u; h2_t h; } c;
    c.h[0] = (_Float16)Whh[(size_t)j * 256 + 2 * e2];
    c.h[1] = (_Float16)Whh[(size_t)j * 256 + 2 * e2 + 1];
    if (e2 < 4 * NREG) {
        Wrg[(size_t)e2 * 768 + j] = c.u;
    } else {
        int ee = e2 - 4 * NREG;
        Wst[((size_t)(ee >> 2) * 768 + j) * 4 + (ee & 3)] = c.u;
    }
}

__global__ void k_prof(const float* __restrict__ profiles, const float* __restrict__ emP_w,
                       const float* __restrict__ emP_b, float* __restrict__ prof)
{
    int b = blockIdx.x, j = threadIdx.x;
    float acc = emP_b[j];
    for (int k = 0; k < PS_; ++k) acc += profiles[(size_t)b * PS_ + k] * emP_w[(size_t)k * PE_ + j];
    prof[(size_t)b * PE_ + j] = acc;
}

__global__ void k_fill_tp(const float* __restrict__ prof,
                          __hip_bfloat16* __restrict__ At_hi, __hip_bfloat16* __restrict__ At_lo)
{
    int idx = blockIdx.x * blockDim.x + threadIdx.x;
    if (idx >= M_ * PE_) return;
    int m = idx >> 6, pe = idx & 63;
    float v = prof[(size_t)(m & (B_ - 1)) * PE_ + pe];
    size_t o = (size_t)m * 320 + 256 + pe;
    bsplit_(v, At_hi[o], At_lo[o]);
}

// ---------------------------------------------------------------------------
// GRAM group attention
// ---------------------------------------------------------------------------
__global__ void k_group_embed(const float* __restrict__ PP, const float* __restrict__ Wa_b,
                              const float* __restrict__ Ua_w, const float* __restrict__ ini_embd,
                              const int* __restrict__ leaves1, const int* __restrict__ anc1,
                              const int* __restrict__ leaves2, const int* __restrict__ anc2,
                              float* __restrict__ embedG)
{
    int n = blockIdx.x;
    int lane = threadIdx.x;
    const int* lv; const int* ac; int L;
    if (n < G1N_) { L = G1L_; lv = leaves1 + (size_t)n * G1L_; ac = anc1 + (size_t)n * G1L_; }
    else { int n2 = n - G1N_; L = G2L_; lv = leaves2 + (size_t)n2 * G2L_; ac = anc2 + (size_t)n2 * G2L_; }

    float score[6]; int ai[6];
    for (int l = 0; l < L; ++l) {
        int li = lv[l]; int av = ac[l]; ai[l] = av;
        float s = 0.0f;
        for (int a = lane; a < A_; a += 64) {
            float hv = tanhf(PP[(size_t)li * 256 + a] + PP[(size_t)av * 256 + 128 + a] + Wa_b[a]);
            s += hv * Ua_w[a];
        }
        for (int o = 32; o; o >>= 1) s += __shfl_xor(s, o);
        score[l] = s;
    }
    float mx = -1e30f;
    for (int l = 0; l < L; ++l) mx = fmaxf(mx, score[l]);
    float w[6], sum = 0.0f;
    for (int l = 0; l < L; ++l) { w[l] = __expf(score[l] - mx); sum += w[l]; }
    float inv = 1.0f / sum;
    for (int e = lane; e < E_; e += 64) {
        float acc = 0.0f;
        for (int l = 0; l < L; ++l) acc += w[l] * inv * ini_embd[(size_t)ai[l] * E_ + e];
        embedG[(size_t)n * E_ + e] = acc;
    }
}

// ---------------------------------------------------------------------------
// GRU scan v5: 256 wgs x 768 threads, 1 sample/wg. gx read from fused Cg
// (stride 1024, offset 256).
// ---------------------------------------------------------------------------
__global__ __launch_bounds__(768, 3)
void k_gru5(const float* __restrict__ Cg, const unsigned int* __restrict__ Wrg,
            const uint4* __restrict__ Wst, const float* __restrict__ bhh,
            const int* __restrict__ X_len, float* __restrict__ gruo,
            __hip_bfloat16* __restrict__ At_hi, __hip_bfloat16* __restrict__ At_lo)
{
    const int b = blockIdx.x;
    const int tid = threadIdx.x;

    __shared__ uint4 h2S[32];
    __shared__ float ghS[768];
    __shared__ float gxnS[256];

    if (tid < 128) ((unsigned int*)h2S)[tid] = 0u;

    uint4 Wr[NREG];
#pragma unroll
    for (int c = 0; c < NREG; ++c) {
        Wr[c].x = Wrg[(size_t)(4 * c + 0) * 768 + tid];
        Wr[c].y = Wrg[(size_t)(4 * c + 1) * 768 + tid];
        Wr[c].z = Wrg[(size_t)(4 * c + 2) * 768 + tid];
        Wr[c].w = Wrg[(size_t)(4 * c + 3) * 768 + tid];
    }

    float hreg = 0.0f;
    const int len = X_len[b];
    const float bj = bhh[tid];
    __syncthreads();

    for (int t = 0; t < T_; ++t) {
        float gxv = Cg[((size_t)t * B_ + b) * 1024 + 256 + tid];

        float a0 = bj;
#pragma unroll
        for (int c = 0; c < 32; ++c) {
            uint4 w = (c < NREG) ? Wr[c] : Wst[(size_t)(c - NREG) * 768 + tid];
            uint4 h = h2S[c];
            a0 = dot2_(w.x, h.x, a0);
            a0 = dot2_(w.y, h.y, a0);
            a0 = dot2_(w.z, h.z, a0);
            a0 = dot2_(w.w, h.w, a0);
        }

        if (tid < 512) ghS[tid] = a0 + gxv;
        else { ghS[tid] = a0; gxnS[tid - 512] = gxv; }
        __syncthreads();

        if (tid < 256) {
            float r  = sigmoidf_(ghS[tid]);
            float z  = sigmoidf_(ghS[256 + tid]);
            float nn = tanhf(gxnS[tid] + r * ghS[512 + tid]);
            float hnew = (1.0f - z) * nn + z * hreg;
            bool msk = (t < len);
            hreg = msk ? hnew : hreg;
            float ov = msk ? hreg : 0.0f;
            size_t m = (size_t)t * B_ + b;
            gruo[m * H_ + tid] = ov;
            size_t o = m * 320 + tid;
            bsplit_(ov, At_hi[o], At_lo[o]);
            float partner = __shfl_xor(hreg, 1);
            if (!(tid & 1)) {
                union { unsigned int u; h2_t h; } p;
                p.h[0] = (_Float16)hreg;
                p.h[1] = (_Float16)partner;
                ((unsigned int*)h2S)[tid >> 1] = p.u;
            }
        }
        __syncthreads();
    }
}

// ---------------------------------------------------------------------------
// Value-memory scan — VM register-resident; era read from fused Cg (stride 1024)
// ---------------------------------------------------------------------------
__global__ __launch_bounds__(256)
void k_mem(const float* __restrict__ slotw, const float* __restrict__ Cg,
           const float* __restrict__ iniVam, float* __restrict__ readv)
{
    const int b = blockIdx.x;
    const int tid = threadIdx.x;
    const int v = tid & (V_ - 1);
    const int sh = tid >> 7;
    const int sbase = sh * 64;

    float VM[64];
#pragma unroll
    for (int i = 0; i < 64; ++i) VM[i] = iniVam[(size_t)(sbase + i) * V_ + v];

    __shared__ float swL[S_];
    __shared__ float eaL[2 * V_];
    __shared__ float part[V_];

    for (int t = 0; t < T_; ++t) {
        size_t m = (size_t)t * B_ + b;
        if (tid < S_) swL[tid] = slotw[m * S_ + tid];
        eaL[tid] = Cg[m * 1024 + tid];
        __syncthreads();

        float er = eaL[v], ad = eaL[V_ + v];
        float p0 = 0.0f, p1 = 0.0f, p2 = 0.0f, p3 = 0.0f;
#pragma unroll
        for (int i = 0; i < 16; ++i) {
            float s0 = swL[sbase + 4 * i];
            float s1 = swL[sbase + 4 * i + 1];
            float s2 = swL[sbase + 4 * i + 2];
            float s3 = swL[sbase + 4 * i + 3];
            float v0 = VM[4 * i], v1 = VM[4 * i + 1], v2 = VM[4 * i + 2], v3 = VM[4 * i + 3];
            p0 += s0 * v0; p1 += s1 * v1; p2 += s2 * v2; p3 += s3 * v3;
            VM[4 * i]     = v0 * (1.0f - s0 * er) + s0 * ad;
            VM[4 * i + 1] = v1 * (1.0f - s1 * er) + s1 * ad;
            VM[4 * i + 2] = v2 * (1.0f - s2 * er) + s2 * ad;
            VM[4 * i + 3] = v3 * (1.0f - s3 * er) + s3 * ad;
        }
        float acc = (p0 + p1) + (p2 + p3);
        if (sh == 1) part[v] = acc;
        __syncthreads();
        if (sh == 0) readv[m * V_ + v] = acc + part[v];
        __syncthreads();
    }
}

// ---------------------------------------------------------------------------
// F = [gruo | read | prof2] as f16 (feeds f16 out-GEMM)
// ---------------------------------------------------------------------------
__global__ __launch_bounds__(256)
void k_build_final(const float* __restrict__ gruo, const float* __restrict__ readv,
                   const float* __restrict__ prof, const float* __restrict__ attnP_w,
                   const float* __restrict__ attnP_b, _Float16* __restrict__ F)
{
    const int m = blockIdx.x;
    const int b = m & (B_ - 1);
    const int tid = threadIdx.x;
    __shared__ float rd[V_];
    __shared__ float pf[PE_];
    if (tid < V_) rd[tid] = readv[(size_t)m * V_ + tid];
    if (tid < PE_) pf[tid] = prof[(size_t)b * PE_ + tid];
    __syncthreads();

    size_t base = (size_t)m * KF_;
    F[base + tid] = (_Float16)gruo[(size_t)m * H_ + tid];
    if (tid < V_) F[base + H_ + tid] = (_Float16)rd[tid];
    if (tid < PE_) {
        float a = attnP_b[tid];
        for (int k = 0; k < PE_; ++k) a += pf[k] * attnP_w[(size_t)k * PE_ + tid];
        for (int k = 0; k < V_; ++k) a += rd[k] * attnP_w[(size_t)(PE_ + k) * PE_ + tid];
        a = fmaxf(a, 0.0f);
        F[base + H_ + V_ + tid] = (_Float16)(pf[tid] * a);
    }
}

// ---------------------------------------------------------------------------
// Softmaxes
// ---------------------------------------------------------------------------
__global__ void k_softmax128(float* __restrict__ C)
{
    const int m = blockIdx.x;
    const size_t base = (size_t)m * S_;
    const int lane = threadIdx.x;
    float a = C[base + lane], b = C[base + 64 + lane];
    float mx = fmaxf(a, b);
    for (int o = 32; o; o >>= 1) mx = fmaxf(mx, __shfl_xor(mx, o));
    float e0 = __expf(a - mx), e1 = __expf(b - mx);
    float s = e0 + e1;
    for (int o = 32; o; o >>= 1) s += __shfl_xor(s, o);
    float inv = 1.0f / s;
    C[base + lane] = e0 * inv;
    C[base + 64 + lane] = e1 * inv;
}

__global__ __launch_bounds__(256)
void k_softmax2000(float* __restrict__ C)
{
    const int m = blockIdx.x;
    const size_t base = (size_t)m * D_;
    const int tid = threadIdx.x;
    const int wid = tid >> 6, lane = tid & 63;
    __shared__ float red[4], red2[4];

    float v[8];
#pragma unroll
    for (int i = 0; i < 8; ++i) {
        int d = i * 256 + tid;
        v[i] = (d < D_) ? C[base + d] : -1e30f;
    }
    float mx = v[0];
#pragma unroll
    for (int i = 1; i < 8; ++i) mx = fmaxf(mx, v[i]);
    for (int o = 32; o; o >>= 1) mx = fmaxf(mx, __shfl_xor(mx, o));
    if (lane == 0) red[wid] = mx;
    __syncthreads();
    mx = fmaxf(fmaxf(red[0], red[1]), fmaxf(red[2], red[3]));

    float sum = 0.0f;
#pragma unroll
    for (int i = 0; i < 8; ++i) { v[i] = __expf(v[i] - mx); sum += v[i]; }
    for (int o = 32; o; o >>= 1) sum += __shfl_xor(sum, o);
    if (lane == 0) red2[wid] = sum;
    __syncthreads();
    sum = red2[0] + red2[1] + red2[2] + red2[3];
    float inv = 1.0f / sum;
#pragma unroll
    for (int i = 0; i < 8; ++i) {
        int d = i * 256 + tid;
        if (d < D_) C[base + d] = v[i] * inv;
    }
}

// ---------------------------------------------------------------------------
// Launch
// ---------------------------------------------------------------------------
extern "C" void kernel_launch(void* const* d_in, const int* in_sizes, int n_in,
                              void* d_out, int out_size, void* d_ws, size_t ws_size,
                              hipStream_t stream)
{
    const float* X        = (const float*)d_in[0];
    const float* profiles = (const float*)d_in[1];
    const float* ini_embd = (const float*)d_in[2];
    const float* Wa_w     = (const float*)d_in[3];
    const float* Wa_b     = (const float*)d_in[4];
    const float* Ua_w     = (const float*)d_in[5];
    const float* gru_Wih  = (const float*)d_in[6];
    const float* gru_Whh  = (const float*)d_in[7];
    const float* gru_bih  = (const float*)d_in[8];
    const float* gru_bhh  = (const float*)d_in[9];
    const float* tranH_w  = (const float*)d_in[10];
    const float* tranH_b  = (const float*)d_in[11];
    const float* out_w    = (const float*)d_in[12];
    const float* out_b    = (const float*)d_in[13];
    const float* erase_w  = (const float*)d_in[14];
    const float* erase_b  = (const float*)d_in[15];
    const float* add_w    = (const float*)d_in[16];
    const float* add_b    = (const float*)d_in[17];
    const float* iniVam   = (const float*)d_in[18];
    const float* emP_w    = (const float*)d_in[19];
    const float* emP_b    = (const float*)d_in[20];
    const float* attnP_w  = (const float*)d_in[21];
    const float* attnP_b  = (const float*)d_in[22];
    const int* KMIds   = (const int*)d_in[23];
    const int* leaves1 = (const int*)d_in[24];
    const int* anc1    = (const int*)d_in[25];
    const int* leaves2 = (const int*)d_in[26];
    const int* anc2    = (const int*)d_in[27];
    const int* mapInfo = (const int*)d_in[28];
    const int* X_len   = (const int*)d_in[29];

    char* ws = (char*)d_ws;
    float* out = (float*)d_out;
    typedef __hip_bfloat16 bf16;

    // ---- workspace layout (bytes) ----
    // R0 (67,108,864): early PP(12.3M)+embG(@12,288,000); then P4 partials
    //   [4][16384][256] f32 (exactly 67,108,864); then Cg [16384][1024] f32
    //   (era cols 0-255, gx cols 256-1023); finally F16 (14,680,064).
    // R1 (16,777,216): gruo f32.
    // R2 (16,777,216): Xe_hi/lo planes; later tran_hi/lo planes.
    // R3 (20,971,520): At_hi/At_lo; later slotw/readv.
    const size_t R0 = 0;
    const size_t R1 = 67108864;
    const size_t R2 = 83886080;
    const size_t R3 = 100663296;
    size_t P = 121634816;
    const size_t EMBHI = P; P += 1048576;
    const size_t EMBLO = P; P += 1048576;
    const size_t OWF  = P; P += 1835008;
    const size_t WGHI = P; P += 524288;     // WG [1024][256] hi
    const size_t WGLO = P; P += 524288;
    const size_t THHI = P; P += 163840;
    const size_t THLO = P; P += 163840;
    const size_t KMHI = P; P += 65536;
    const size_t KMLO = P; P += 65536;
    const size_t WRG  = P; P += 344064;
    const size_t WST  = P; P += 49152;
    const size_t PROF = P; P += 65536;
    const size_t BIAS = P; P += 4096;
    const size_t W2O  = P; P += 262144;

    float* PP      = (float*)(ws + R0);
    float* embG    = (float*)(ws + R0 + 12288000);
    float* P4      = (float*)(ws + R0);
    float* Cg      = (float*)(ws + R0);
    _Float16* F16  = (_Float16*)(ws + R0);
    float* gruo    = (float*)(ws + R1);
    bf16*  Xe_hi   = (bf16*)(ws + R2);
    bf16*  Xe_lo   = (bf16*)(ws + R2 + 8388608);
    bf16*  tran_hi = (bf16*)(ws + R2);
    bf16*  tran_lo = (bf16*)(ws + R2 + 8388608);
    bf16*  At_hi   = (bf16*)(ws + R3);
    bf16*  At_lo   = (bf16*)(ws + R3 + 10485760);
    float* slotw   = (float*)(ws + R3);
    float* readv   = (float*)(ws + R3 + 10485760);
    bf16*  EMBhi = (bf16*)(ws + EMBHI); bf16* EMBlo = (bf16*)(ws + EMBLO);
    _Float16* OWf = (_Float16*)(ws + OWF);
    bf16*  WGhi = (bf16*)(ws + WGHI); bf16* WGlo = (bf16*)(ws + WGLO);
    bf16*  THhi = (bf16*)(ws + THHI); bf16* THlo = (bf16*)(ws + THLO);
    bf16*  KMhi = (bf16*)(ws + KMHI); bf16* KMlo = (bf16*)(ws + KMLO);
    unsigned int* Wrg = (unsigned int*)(ws + WRG);
    unsigned int* Wst = (unsigned int*)(ws + WST);
    float* prof  = (float*)(ws + PROF);
    float* biasG = (float*)(ws + BIAS);
    float* W2p   = (float*)(ws + W2O);

    // ---- weight packs ----
    k_pack_w2<<<(E_ * 2 * A_ + 255) / 256, 256, 0, stream>>>(Wa_w, W2p);
    k_wg_split<<<(1024 * 256 + 255) / 256, 256, 0, stream>>>(
        erase_w, add_w, gru_Wih, erase_b, add_b, gru_bih, WGhi, WGlo, biasG);
    k_tranHT_split<<<(256 * 320 + 255) / 256, 256, 0, stream>>>(tranH_w, THhi, THlo);
    k_outWT_f16<<<(2048 * 448 + 255) / 256, 256, 0, stream>>>(out_w, OWf);
    k_km_split<<<(S_ * E_ + 255) / 256, 256, 0, stream>>>(ini_embd, KMIds, KMhi, KMlo);
    k_wgru_pack<<<(768 * 128 + 255) / 256, 256, 0, stream>>>(gru_Whh, Wrg, Wst);
    k_prof<<<B_, PE_, 0, stream>>>(profiles, emP_w, emP_b, prof);

    // ---- ontology attention -> embedMat planes ----
    {
        dim3 blk(16, 16);
        dim3 grid(4, (TN_ + 63) / 64);
        k_gemm<64, 64, 16, 4, 4><<<grid, blk, 0, stream>>>(ini_embd, W2p, PP, TN_, 256, E_);
    }
    k_group_embed<<<G1N_ + G2N_, 64, 0, stream>>>(PP, Wa_b, Ua_w, ini_embd,
                                                  leaves1, anc1, leaves2, anc2, embG);
    k_embMT<<<(256 * 2048) / 256, 256, 0, stream>>>(embG, mapInfo, EMBhi, EMBlo);

    // ---- Xe = X @ embM : split-K fused GEMM -> partials -> reduce+split ----
    k_mgemmX<<<SK_ * 256, 256, 0, stream>>>(X, EMBhi, EMBlo, P4);
    k_reduceX<<<(M_ * 256) / 256, 256, 0, stream>>>(P4, Xe_hi, Xe_lo);

    // ---- Cg = [era | gx] = gates/linear(Xe @ WG + biasG) fused GEMM ----
    k_mgemm3<2, false, 0, 3, 0><<<128 * 8, 256, 0, stream>>>(Xe_hi, Xe_lo, WGhi, WGlo,
        biasG, Cg, nullptr, nullptr, 256, 1024, 8);

    // ---- GRU scan v5 (gx from Cg) ----
    k_gru5<<<256, 768, 0, stream>>>(Cg, Wrg, (const uint4*)Wst, gru_bhh, X_len,
                                    gruo, At_hi, At_lo);
    k_fill_tp<<<(M_ * PE_) / 256, 256, 0, stream>>>(prof, At_hi, At_lo);

    // ---- tran = [gruo|prof] @ tranH + b ----
    k_mgemm3<0, false, 1, 3, 0><<<128 * 2, 256, 0, stream>>>(At_hi, At_lo, THhi, THlo,
        tranH_b, nullptr, tran_hi, tran_lo, 320, 256, 2);

    // ---- slot logits = tran @ KM^T ----
    k_mgemm3<0, false, 0, 3, 0><<<128 * 1, 256, 0, stream>>>(tran_hi, tran_lo, KMhi, KMlo,
        nullptr, slotw, nullptr, nullptr, 256, 128, 1);

    k_softmax128<<<M_, 64, 0, stream>>>(slotw);
    k_mem<<<B_, 256, 0, stream>>>(slotw, Cg, iniVam, readv);
    k_build_final<<<M_, 256, 0, stream>>>(gruo, readv, prof, attnP_w, attnP_b, F16);

    // ---- logits = F @ out_w + out_b (f16 1-phase MFMA) ----
    k_mgemm3<0, false, 0, 1, 1><<<128 * 16, 256, 0, stream>>>(
        (const bf16*)F16, nullptr, (const bf16*)OWf, nullptr,
        out_b, out, nullptr, nullptr, 448, 2000, 16);

    k_softmax2000<<<M_, 256, 0, stream>>>(out);
}

// Round 10
// 654.640 us; speedup vs baseline: 1.0184x; 1.0184x over previous
//
#include <hip/hip_runtime.h>
#include <hip/hip_bf16.h>
#include <cmath>

#define T_  64
#define B_  256
#define D_  2000
#define TN_ 3000
#define E_  256
#define H_  256
#define A_  128
#define V_  128
#define PS_ 64
#define PE_ 64
#define S_  128
#define G1N_ 1500
#define G1L_ 4
#define G2N_ 1500
#define G2L_ 6
#define M_  (T_ * B_)
#define KF_ (H_ + V_ + PE_)
#define NREG 28   // Whh f16 chunks held in registers (of 32)
#define SK_ 4     // split-K chunks for Xe GEMM

typedef __attribute__((ext_vector_type(8))) short short8_t;
typedef __attribute__((ext_vector_type(4))) float floatx4;
typedef _Float16 __attribute__((ext_vector_type(2))) h2_t;
typedef _Float16 __attribute__((ext_vector_type(8))) h8_t;

static __device__ __forceinline__ float sigmoidf_(float x) {
    return 1.0f / (1.0f + __expf(-x));
}

static __device__ __forceinline__ void bsplit_(float v, __hip_bfloat16& hi, __hip_bfloat16& lo) {
    hi = __float2bfloat16(v);
    lo = __float2bfloat16(v - __bfloat162float(hi));
}

static __device__ __forceinline__ float dot2_(unsigned int w, unsigned int h, float acc) {
    union { unsigned int u; h2_t h; } cw, ch;
    cw.u = w; ch.u = h;
#if __has_builtin(__builtin_amdgcn_fdot2)
    return __builtin_amdgcn_fdot2(cw.h, ch.h, acc, false);
#else
    return acc + (float)cw.h[0] * (float)ch.h[0] + (float)cw.h[1] * (float)ch.h[1];
#endif
}

template<int DT>
static __device__ __forceinline__ floatx4 mfma16_(short8_t a, short8_t b, floatx4 c) {
    if constexpr (DT == 0) {
        return __builtin_amdgcn_mfma_f32_16x16x32_bf16(a, b, c, 0, 0, 0);
    } else {
        union { short8_t s; h8_t h; } ua, ub;
        ua.s = a; ub.s = b;
        return __builtin_amdgcn_mfma_f32_16x16x32_f16(ua.h, ub.h, c, 0, 0, 0);
    }
}

// ---------------------------------------------------------------------------
// Split MFMA GEMM: C = A @ B. DT=0: bf16 planes (NPH=3 -> fp32-grade).
// DT=1: f16 planes, NPH=1 (f16 hi-only, ~2^-12 accurate).
// B given as BT[Npad][K] row-major. M mult 128, K mult 32, Npad = nblk*128.
// EPI 1: sigmoid col<128 else tanh. EPI 2: sigmoid col<128, tanh col<256.
// OUTMODE 0: f32 Cf (ACCUM adds). 1: bf16 split (Chi,Clo). 2: f16 (Chi cast).
// ---------------------------------------------------------------------------
template<int EPI, bool ACCUM, int OUTMODE, int NPH, int DT>
__global__ __launch_bounds__(256)
void k_mgemm3(const __hip_bfloat16* __restrict__ Ahi, const __hip_bfloat16* __restrict__ Alo,
              const __hip_bfloat16* __restrict__ Bhi, const __hip_bfloat16* __restrict__ Blo,
              const float* __restrict__ bias, float* __restrict__ Cf,
              __hip_bfloat16* __restrict__ Chi, __hip_bfloat16* __restrict__ Clo,
              int K, int Nreal, int nblk)
{
    __shared__ __align__(16) short As[4096];
    __shared__ __align__(16) short Bs[4096];

    const int tid  = threadIdx.x;
    const int lane = tid & 63;
    const int w    = tid >> 6;
    const int wm   = w >> 1, wn = w & 1;
    const int lr   = lane & 15;
    const int lkc  = lane >> 4;

    const int bx = blockIdx.x;
    const int m0 = (bx / nblk) * 128;
    const int n0 = (bx % nblk) * 128;

    const int fa = 2 * w;
    const size_t aoff0 = (size_t)(m0 + fa * 16 + lr) * K + lkc * 8;
    const size_t aoff1 = aoff0 + (size_t)16 * K;
    const size_t boff0 = (size_t)(n0 + fa * 16 + lr) * K + lkc * 8;
    const size_t boff1 = boff0 + (size_t)16 * K;

    floatx4 acc[4][4];
#pragma unroll
    for (int i = 0; i < 4; ++i)
#pragma unroll
        for (int j = 0; j < 4; ++j) acc[i][j] = floatx4{0.f, 0.f, 0.f, 0.f};

#pragma unroll 1
    for (int ph = 0; ph < NPH; ++ph) {
        const __hip_bfloat16* Ap = (ph == 2) ? Alo : Ahi;
        const __hip_bfloat16* Bp = (ph == 1) ? Blo : Bhi;

        short8_t ra0 = *(const short8_t*)(const void*)(Ap + aoff0);
        short8_t ra1 = *(const short8_t*)(const void*)(Ap + aoff1);
        short8_t rb0 = *(const short8_t*)(const void*)(Bp + boff0);
        short8_t rb1 = *(const short8_t*)(const void*)(Bp + boff1);

        for (int k0 = 0; k0 < K; k0 += 32) {
            __syncthreads();
            *(short8_t*)(void*)&As[(fa    ) * 512 + lane * 8] = ra0;
            *(short8_t*)(void*)&As[(fa + 1) * 512 + lane * 8] = ra1;
            *(short8_t*)(void*)&Bs[(fa    ) * 512 + lane * 8] = rb0;
            *(short8_t*)(void*)&Bs[(fa + 1) * 512 + lane * 8] = rb1;
            __syncthreads();

            if (k0 + 32 < K) {
                int kn = k0 + 32;
                ra0 = *(const short8_t*)(const void*)(Ap + aoff0 + kn);
                ra1 = *(const short8_t*)(const void*)(Ap + aoff1 + kn);
                rb0 = *(const short8_t*)(const void*)(Bp + boff0 + kn);
                rb1 = *(const short8_t*)(const void*)(Bp + boff1 + kn);
            }

            short8_t af[4], bf[4];
#pragma unroll
            for (int i = 0; i < 4; ++i)
                af[i] = *(const short8_t*)(const void*)&As[(wm * 4 + i) * 512 + lane * 8];
#pragma unroll
            for (int j = 0; j < 4; ++j)
                bf[j] = *(const short8_t*)(const void*)&Bs[(wn * 4 + j) * 512 + lane * 8];
#pragma unroll
            for (int i = 0; i < 4; ++i)
#pragma unroll
                for (int j = 0; j < 4; ++j)
                    acc[i][j] = mfma16_<DT>(af[i], bf[j], acc[i][j]);
        }
    }

    // C/D layout (m89-verified): col=lane&15, row=(lane>>4)*4+r
#pragma unroll
    for (int i = 0; i < 4; ++i) {
        const int row = m0 + wm * 64 + i * 16 + (lane >> 4) * 4;
#pragma unroll
        for (int j = 0; j < 4; ++j) {
            const int col = n0 + wn * 64 + j * 16 + (lane & 15);
            if (col < Nreal) {
                float bv = bias ? bias[col] : 0.0f;
#pragma unroll
                for (int r = 0; r < 4; ++r) {
                    float v = acc[i][j][r] + bv;
                    if (EPI == 1) v = (col < 128) ? sigmoidf_(v) : tanhf(v);
                    if (EPI == 2) {
                        if (col < 128) v = sigmoidf_(v);
                        else if (col < 256) v = tanhf(v);
                    }
                    size_t o = (size_t)(row + r) * Nreal + col;
                    if (OUTMODE == 0) {
                        if (ACCUM) v += Cf[o];
                        Cf[o] = v;
                    } else if (OUTMODE == 1) {
                        __hip_bfloat16 h, l;
                        bsplit_(v, h, l);
                        Chi[o] = h; Clo[o] = l;
                    } else {
                        ((_Float16*)Chi)[o] = (_Float16)v;
                    }
                }
            }
        }
    }
}

// ---------------------------------------------------------------------------
// Fused Xe GEMM v2, split-K, f16 2-phase: A = f32 X converted on-the-fly to a
// SINGLE f16 LDS plane; B = f16 hi/lo planes. Phases: A*Bhi + A*Blo (f16 MFMA,
// f32 accumulate). Error carried: only X's f16 rounding (~0.003 sigma on Xe).
// grid = SK_ * 256; writes f32 partials P4[kc][16384][256].
// ---------------------------------------------------------------------------
__global__ __launch_bounds__(256)
void k_mgemmX(const float* __restrict__ A,
              const _Float16* __restrict__ Bhi, const _Float16* __restrict__ Blo,
              float* __restrict__ P4)
{
    const int KP = 2048, KR = 2000, NN = 256, nblk = 2;
    const int KC = 2048 / SK_;               // 512
    __shared__ __align__(16) short Ah[4096];
    __shared__ __align__(16) short Bh[4096];
    __shared__ __align__(16) short Bl[4096];

    const int tid  = threadIdx.x;
    const int lane = tid & 63;
    const int w    = tid >> 6;
    const int wm   = w >> 1, wn = w & 1;
    const int lr   = lane & 15;
    const int lkc  = lane >> 4;

    const int kc = blockIdx.x >> 8;          // k-chunk
    const int bx = blockIdx.x & 255;
    const int m0 = (bx / nblk) * 128;
    const int n0 = (bx % nblk) * 128;
    const int KC0 = kc * KC;
    float* dst = P4 + (size_t)kc * (M_ * 256);

    const int fa = 2 * w;
    const float* arow0 = A + (size_t)(m0 + fa * 16 + lr) * KR;
    const float* arow1 = arow0 + (size_t)16 * KR;
    const size_t boff0 = (size_t)(n0 + fa * 16 + lr) * KP + lkc * 8;
    const size_t boff1 = boff0 + (size_t)16 * KP;

    floatx4 acc[4][4];
#pragma unroll
    for (int i = 0; i < 4; ++i)
#pragma unroll
        for (int j = 0; j < 4; ++j) acc[i][j] = floatx4{0.f, 0.f, 0.f, 0.f};

    float a0v[8], a1v[8];
    short8_t bh0, bh1, bl0, bl1;

#define LOADA8(ROW, KB, DST)                                                  \
    if ((KB) + 7 < KR) {                                                      \
        float4 p_ = *(const float4*)((ROW) + (KB));                           \
        float4 q_ = *(const float4*)((ROW) + (KB) + 4);                       \
        DST[0]=p_.x; DST[1]=p_.y; DST[2]=p_.z; DST[3]=p_.w;                   \
        DST[4]=q_.x; DST[5]=q_.y; DST[6]=q_.z; DST[7]=q_.w;                   \
    } else {                                                                  \
        _Pragma("unroll")                                                     \
        for (int ii = 0; ii < 8; ++ii)                                        \
            DST[ii] = ((KB) + ii < KR) ? (ROW)[(KB) + ii] : 0.0f;             \
    }

    {
        const int kb = KC0 + lkc * 8;
        LOADA8(arow0, kb, a0v)
        LOADA8(arow1, kb, a1v)
        bh0 = *(const short8_t*)(const void*)(Bhi + boff0 + KC0);
        bh1 = *(const short8_t*)(const void*)(Bhi + boff1 + KC0);
        bl0 = *(const short8_t*)(const void*)(Blo + boff0 + KC0);
        bl1 = *(const short8_t*)(const void*)(Blo + boff1 + KC0);
    }

    for (int k0 = KC0; k0 < KC0 + KC; k0 += 32) {
        __syncthreads();
        {
            short h8a[8], h8b[8];
#pragma unroll
            for (int i = 0; i < 8; ++i) {
                union { _Float16 h; short s; } ca, cb;
                ca.h = (_Float16)a0v[i];
                cb.h = (_Float16)a1v[i];
                h8a[i] = ca.s; h8b[i] = cb.s;
            }
            *(short8_t*)(void*)&Ah[(fa    ) * 512 + lane * 8] = *(short8_t*)h8a;
            *(short8_t*)(void*)&Ah[(fa + 1) * 512 + lane * 8] = *(short8_t*)h8b;
            *(short8_t*)(void*)&Bh[(fa    ) * 512 + lane * 8] = bh0;
            *(short8_t*)(void*)&Bh[(fa + 1) * 512 + lane * 8] = bh1;
            *(short8_t*)(void*)&Bl[(fa    ) * 512 + lane * 8] = bl0;
            *(short8_t*)(void*)&Bl[(fa + 1) * 512 + lane * 8] = bl1;
        }
        __syncthreads();

        if (k0 + 32 < KC0 + KC) {
            const int kb = k0 + 32 + lkc * 8;
            LOADA8(arow0, kb, a0v)
            LOADA8(arow1, kb, a1v)
            bh0 = *(const short8_t*)(const void*)(Bhi + boff0 + k0 + 32);
            bh1 = *(const short8_t*)(const void*)(Bhi + boff1 + k0 + 32);
            bl0 = *(const short8_t*)(const void*)(Blo + boff0 + k0 + 32);
            bl1 = *(const short8_t*)(const void*)(Blo + boff1 + k0 + 32);
        }

        short8_t af[4], bfh[4], bfl[4];
#pragma unroll
        for (int i = 0; i < 4; ++i) {
            af[i]  = *(const short8_t*)(const void*)&Ah[(wm * 4 + i) * 512 + lane * 8];
            bfh[i] = *(const short8_t*)(const void*)&Bh[(wn * 4 + i) * 512 + lane * 8];
        }
#pragma unroll
        for (int i = 0; i < 4; ++i)
#pragma unroll
            for (int j = 0; j < 4; ++j)
                acc[i][j] = mfma16_<1>(af[i], bfh[j], acc[i][j]);
#pragma unroll
        for (int j = 0; j < 4; ++j)
            bfl[j] = *(const short8_t*)(const void*)&Bl[(wn * 4 + j) * 512 + lane * 8];
#pragma unroll
        for (int i = 0; i < 4; ++i)
#pragma unroll
            for (int j = 0; j < 4; ++j)
                acc[i][j] = mfma16_<1>(af[i], bfl[j], acc[i][j]);
    }
#undef LOADA8

#pragma unroll
    for (int i = 0; i < 4; ++i) {
        const int row = m0 + wm * 64 + i * 16 + (lane >> 4) * 4;
#pragma unroll
        for (int j = 0; j < 4; ++j) {
            const int col = n0 + wn * 64 + j * 16 + (lane & 15);
#pragma unroll
            for (int r = 0; r < 4; ++r)
                dst[(size_t)(row + r) * NN + col] = acc[i][j][r];
        }
    }
}

// reduce SK_ partials -> Xe bf16 planes
__global__ void k_reduceX(const float* __restrict__ P4,
                          __hip_bfloat16* __restrict__ hi, __hip_bfloat16* __restrict__ lo)
{
    int idx = blockIdx.x * blockDim.x + threadIdx.x;
    if (idx >= M_ * 256) return;
    const size_t CH = (size_t)M_ * 256;
    float v = P4[idx];
#pragma unroll
    for (int c = 1; c < SK_; ++c) v += P4[idx + c * CH];
    bsplit_(v, hi[idx], lo[idx]);
}

// ---------------------------------------------------------------------------
// fp32 tiled GEMM (PP = ini_embd @ W2 only)
// ---------------------------------------------------------------------------
template<int BM, int BN, int BK, int TM, int TN>
__global__ __launch_bounds__(256)
void k_gemm(const float* __restrict__ A, const float* __restrict__ B,
            float* __restrict__ C, int M, int N, int K)
{
    __shared__ float As[BK][BM + 4];
    __shared__ float Bs[BK][BN + 4];
    const int tid = threadIdx.y * blockDim.x + threadIdx.x;
    const int m0 = blockIdx.y * BM;
    const int n0 = blockIdx.x * BN;
    float acc[TM][TN];
#pragma unroll
    for (int i = 0; i < TM; ++i)
#pragma unroll
        for (int j = 0; j < TN; ++j) acc[i][j] = 0.0f;
    for (int k0 = 0; k0 < K; k0 += BK) {
#pragma unroll
        for (int i = tid; i < BM * BK; i += 256) {
            int r = i / BK, c = i % BK;
            int m = m0 + r;
            As[c][r] = (m < M) ? A[(size_t)m * K + k0 + c] : 0.0f;
        }
#pragma unroll
        for (int i = tid; i < BK * BN; i += 256) {
            int r = i / BN, c = i % BN;
            Bs[r][c] = B[(size_t)(k0 + r) * N + n0 + c];
        }
        __syncthreads();
#pragma unroll
        for (int kk = 0; kk < BK; ++kk) {
            float a[TM], b[TN];
#pragma unroll
            for (int i = 0; i < TM; ++i) a[i] = As[kk][threadIdx.y * TM + i];
#pragma unroll
            for (int j = 0; j < TN; ++j) b[j] = Bs[kk][threadIdx.x * TN + j];
#pragma unroll
            for (int i = 0; i < TM; ++i)
#pragma unroll
                for (int j = 0; j < TN; ++j) acc[i][j] += a[i] * b[j];
        }
        __syncthreads();
    }
#pragma unroll
    for (int i = 0; i < TM; ++i) {
        int m = m0 + threadIdx.y * TM + i;
        if (m >= M) continue;
#pragma unroll
        for (int j = 0; j < TN; ++j)
            C[(size_t)m * N + n0 + threadIdx.x * TN + j] = acc[i][j];
    }
}

// ---------------------------------------------------------------------------
// Pack / convert / split kernels
// ---------------------------------------------------------------------------
__global__ void k_pack_w2(const float* __restrict__ Wa_w, float* __restrict__ W2)
{
    int idx = blockIdx.x * blockDim.x + threadIdx.x;
    if (idx >= E_ * 2 * A_) return;
    int e = idx / (2 * A_), j = idx % (2 * A_);
    W2[idx] = (j < A_) ? Wa_w[(size_t)e * A_ + j]
                       : Wa_w[(size_t)(E_ + e) * A_ + (j - A_)];
}

// WG[1024][256] split planes: n<128 erase_w[k][n]; n<256 add_w[k][n-128];
// n>=256 Wih[n-256][k].  biasG = [erase_b | add_b | gru_bih]
__global__ void k_wg_split(const float* __restrict__ erase_w, const float* __restrict__ add_w,
                           const float* __restrict__ Wih,
                           const float* __restrict__ erase_b, const float* __restrict__ add_b,
                           const float* __restrict__ bih,
                           __hip_bfloat16* __restrict__ WGhi, __hip_bfloat16* __restrict__ WGlo,
                           float* __restrict__ biasG)
{
    int idx = blockIdx.x * blockDim.x + threadIdx.x;
    if (idx < 1024 * 256) {
        int n = idx >> 8, k = idx & 255;
        float v;
        if (n < 128)      v = erase_w[(size_t)k * V_ + n];
        else if (n < 256) v = add_w[(size_t)k * V_ + (n - 128)];
        else              v = Wih[(size_t)(n - 256) * 256 + k];
        bsplit_(v, WGhi[idx], WGlo[idx]);
    }
    if (idx < 1024)
        biasG[idx] = (idx < 128) ? erase_b[idx]
                   : (idx < 256) ? add_b[idx - 128]
                                 : bih[idx - 256];
}

__global__ void k_tranHT_split(const float* __restrict__ tranH_w,
                               __hip_bfloat16* __restrict__ hi, __hip_bfloat16* __restrict__ lo)
{
    int idx = blockIdx.x * blockDim.x + threadIdx.x;
    if (idx >= 256 * 320) return;
    int n = idx / 320, k = idx % 320;
    bsplit_(tranH_w[(size_t)k * 256 + n], hi[idx], lo[idx]);
}

// out_w transposed -> single f16 plane
__global__ void k_outWT_f16(const float* __restrict__ out_w, _Float16* __restrict__ dst)
{
    int idx = blockIdx.x * blockDim.x + threadIdx.x;
    if (idx >= 2048 * 448) return;
    int n = idx / 448, k = idx % 448;
    float v = (n < D_) ? out_w[(size_t)k * D_ + n] : 0.0f;
    dst[idx] = (_Float16)v;
}

__global__ void k_km_split(const float* __restrict__ ini_embd, const int* __restrict__ KMIds,
                           __hip_bfloat16* __restrict__ hi, __hip_bfloat16* __restrict__ lo)
{
    int idx = blockIdx.x * blockDim.x + threadIdx.x;
    if (idx >= S_ * E_) return;
    int s = idx / E_, k = idx % E_;
    bsplit_(ini_embd[(size_t)KMIds[s] * E_ + k], hi[idx], lo[idx]);
}

// embMT full: dst[e][d] = f16 split of embG[mapInfo[d]][e], d<2000 else 0
__global__ void k_embMT_f16(const float* __restrict__ embG, const int* __restrict__ mapInfo,
                            _Float16* __restrict__ hi, _Float16* __restrict__ lo)
{
    int idx = blockIdx.x * blockDim.x + threadIdx.x;
    if (idx >= 256 * 2048) return;
    int e = idx >> 11, d = idx & 2047;
    float v = (d < D_) ? embG[(size_t)mapInfo[d] * E_ + e] : 0.0f;
    _Float16 h = (_Float16)v;
    hi[idx] = h;
    lo[idx] = (_Float16)(v - (float)h);
}

// Whh[j][e] f32 -> f16 pairs. e2 < 4*NREG -> Wrg[e2][768]; else Wst chunks
__global__ void k_wgru_pack(const float* __restrict__ Whh,
                            unsigned int* __restrict__ Wrg, unsigned int* __restrict__ Wst)
{
    int idx = blockIdx.x * blockDim.x + threadIdx.x;
    if (idx >= 768 * 128) return;
    int j = idx / 128, e2 = idx % 128;
    union { unsigned int u; h2_t h; } c;
    c.h[0] = (_Float16)Whh[(size_t)j * 256 + 2 * e2];
    c.h[1] = (_Float16)Whh[(size_t)j * 256 + 2 * e2 + 1];
    if (e2 < 4 * NREG) {
        Wrg[(size_t)e2 * 768 + j] = c.u;
    } else {
        int ee = e2 - 4 * NREG;
        Wst[((size_t)(ee >> 2) * 768 + j) * 4 + (ee & 3)] = c.u;
    }
}

__global__ void k_prof(const float* __restrict__ profiles, const float* __restrict__ emP_w,
                       const float* __restrict__ emP_b, float* __restrict__ prof)
{
    int b = blockIdx.x, j = threadIdx.x;
    float acc = emP_b[j];
    for (int k = 0; k < PS_; ++k) acc += profiles[(size_t)b * PS_ + k] * emP_w[(size_t)k * PE_ + j];
    prof[(size_t)b * PE_ + j] = acc;
}

__global__ void k_fill_tp(const float* __restrict__ prof,
                          __hip_bfloat16* __restrict__ At_hi, __hip_bfloat16* __restrict__ At_lo)
{
    int idx = blockIdx.x * blockDim.x + threadIdx.x;
    if (idx >= M_ * PE_) return;
    int m = idx >> 6, pe = idx & 63;
    float v = prof[(size_t)(m & (B_ - 1)) * PE_ + pe];
    size_t o = (size_t)m * 320 + 256 + pe;
    bsplit_(v, At_hi[o], At_lo[o]);
}

// ---------------------------------------------------------------------------
// GRAM group attention
// ---------------------------------------------------------------------------
__global__ void k_group_embed(const float* __restrict__ PP, const float* __restrict__ Wa_b,
                              const float* __restrict__ Ua_w, const float* __restrict__ ini_embd,
                              const int* __restrict__ leaves1, const int* __restrict__ anc1,
                              const int* __restrict__ leaves2, const int* __restrict__ anc2,
                              float* __restrict__ embedG)
{
    int n = blockIdx.x;
    int lane = threadIdx.x;
    const int* lv; const int* ac; int L;
    if (n < G1N_) { L = G1L_; lv = leaves1 + (size_t)n * G1L_; ac = anc1 + (size_t)n * G1L_; }
    else { int n2 = n - G1N_; L = G2L_; lv = leaves2 + (size_t)n2 * G2L_; ac = anc2 + (size_t)n2 * G2L_; }

    float score[6]; int ai[6];
    for (int l = 0; l < L; ++l) {
        int li = lv[l]; int av = ac[l]; ai[l] = av;
        float s = 0.0f;
        for (int a = lane; a < A_; a += 64) {
            float hv = tanhf(PP[(size_t)li * 256 + a] + PP[(size_t)av * 256 + 128 + a] + Wa_b[a]);
            s += hv * Ua_w[a];
        }
        for (int o = 32; o; o >>= 1) s += __shfl_xor(s, o);
        score[l] = s;
    }
    float mx = -1e30f;
    for (int l = 0; l < L; ++l) mx = fmaxf(mx, score[l]);
    float w[6], sum = 0.0f;
    for (int l = 0; l < L; ++l) { w[l] = __expf(score[l] - mx); sum += w[l]; }
    float inv = 1.0f / sum;
    for (int e = lane; e < E_; e += 64) {
        float acc = 0.0f;
        for (int l = 0; l < L; ++l) acc += w[l] * inv * ini_embd[(size_t)ai[l] * E_ + e];
        embedG[(size_t)n * E_ + e] = acc;
    }
}

// ---------------------------------------------------------------------------
// GRU scan v5: 256 wgs x 768 threads, 1 sample/wg. gx from fused Cg
// (stride 1024, offset 256).
// ---------------------------------------------------------------------------
__global__ __launch_bounds__(768, 3)
void k_gru5(const float* __restrict__ Cg, const unsigned int* __restrict__ Wrg,
            const uint4* __restrict__ Wst, const float* __restrict__ bhh,
            const int* __restrict__ X_len, float* __restrict__ gruo,
            __hip_bfloat16* __restrict__ At_hi, __hip_bfloat16* __restrict__ At_lo)
{
    const int b = blockIdx.x;
    const int tid = threadIdx.x;

    __shared__ uint4 h2S[32];
    __shared__ float ghS[768];
    __shared__ float gxnS[256];

    if (tid < 128) ((unsigned int*)h2S)[tid] = 0u;

    uint4 Wr[NREG];
#pragma unroll
    for (int c = 0; c < NREG; ++c) {
        Wr[c].x = Wrg[(size_t)(4 * c + 0) * 768 + tid];
        Wr[c].y = Wrg[(size_t)(4 * c + 1) * 768 + tid];
        Wr[c].z = Wrg[(size_t)(4 * c + 2) * 768 + tid];
        Wr[c].w = Wrg[(size_t)(4 * c + 3) * 768 + tid];
    }

    float hreg = 0.0f;
    const int len = X_len[b];
    const float bj = bhh[tid];
    __syncthreads();

    for (int t = 0; t < T_; ++t) {
        float gxv = Cg[((size_t)t * B_ + b) * 1024 + 256 + tid];

        float a0 = bj;
#pragma unroll
        for (int c = 0; c < 32; ++c) {
            uint4 w = (c < NREG) ? Wr[c] : Wst[(size_t)(c - NREG) * 768 + tid];
            uint4 h = h2S[c];
            a0 = dot2_(w.x, h.x, a0);
            a0 = dot2_(w.y, h.y, a0);
            a0 = dot2_(w.z, h.z, a0);
            a0 = dot2_(w.w, h.w, a0);
        }

        if (tid < 512) ghS[tid] = a0 + gxv;
        else { ghS[tid] = a0; gxnS[tid - 512] = gxv; }
        __syncthreads();

        if (tid < 256) {
            float r  = sigmoidf_(ghS[tid]);
            float z  = sigmoidf_(ghS[256 + tid]);
            float nn = tanhf(gxnS[tid] + r * ghS[512 + tid]);
            float hnew = (1.0f - z) * nn + z * hreg;
            bool msk = (t < len);
            hreg = msk ? hnew : hreg;
            float ov = msk ? hreg : 0.0f;
            size_t m = (size_t)t * B_ + b;
            gruo[m * H_ + tid] = ov;
            size_t o = m * 320 + tid;
            bsplit_(ov, At_hi[o], At_lo[o]);
            float partner = __shfl_xor(hreg, 1);
            if (!(tid & 1)) {
                union { unsigned int u; h2_t h; } p;
                p.h[0] = (_Float16)hreg;
                p.h[1] = (_Float16)partner;
                ((unsigned int*)h2S)[tid >> 1] = p.u;
            }
        }
        __syncthreads();
    }
}

// ---------------------------------------------------------------------------
// Value-memory scan — VM register-resident; era from fused Cg (stride 1024)
// ---------------------------------------------------------------------------
__global__ __launch_bounds__(256)
void k_mem(const float* __restrict__ slotw, const float* __restrict__ Cg,
           const float* __restrict__ iniVam, float* __restrict__ readv)
{
    const int b = blockIdx.x;
    const int tid = threadIdx.x;
    const int v = tid & (V_ - 1);
    const int sh = tid >> 7;
    const int sbase = sh * 64;

    float VM[64];
#pragma unroll
    for (int i = 0; i < 64; ++i) VM[i] = iniVam[(size_t)(sbase + i) * V_ + v];

    __shared__ float swL[S_];
    __shared__ float eaL[2 * V_];
    __shared__ float part[V_];

    for (int t = 0; t < T_; ++t) {
        size_t m = (size_t)t * B_ + b;
        if (tid < S_) swL[tid] = slotw[m * S_ + tid];
        eaL[tid] = Cg[m * 1024 + tid];
        __syncthreads();

        float er = eaL[v], ad = eaL[V_ + v];
        float p0 = 0.0f, p1 = 0.0f, p2 = 0.0f, p3 = 0.0f;
#pragma unroll
        for (int i = 0; i < 16; ++i) {
            float s0 = swL[sbase + 4 * i];
            float s1 = swL[sbase + 4 * i + 1];
            float s2 = swL[sbase + 4 * i + 2];
            float s3 = swL[sbase + 4 * i + 3];
            float v0 = VM[4 * i], v1 = VM[4 * i + 1], v2 = VM[4 * i + 2], v3 = VM[4 * i + 3];
            p0 += s0 * v0; p1 += s1 * v1; p2 += s2 * v2; p3 += s3 * v3;
            VM[4 * i]     = v0 * (1.0f - s0 * er) + s0 * ad;
            VM[4 * i + 1] = v1 * (1.0f - s1 * er) + s1 * ad;
            VM[4 * i + 2] = v2 * (1.0f - s2 * er) + s2 * ad;
            VM[4 * i + 3] = v3 * (1.0f - s3 * er) + s3 * ad;
        }
        float acc = (p0 + p1) + (p2 + p3);
        if (sh == 1) part[v] = acc;
        __syncthreads();
        if (sh == 0) readv[m * V_ + v] = acc + part[v];
        __syncthreads();
    }
}

// ---------------------------------------------------------------------------
// F = [gruo | read | prof2] as f16 (feeds f16 out-GEMM)
// ---------------------------------------------------------------------------
__global__ __launch_bounds__(256)
void k_build_final(const float* __restrict__ gruo, const float* __restrict__ readv,
                   const float* __restrict__ prof, const float* __restrict__ attnP_w,
                   const float* __restrict__ attnP_b, _Float16* __restrict__ F)
{
    const int m = blockIdx.x;
    const int b = m & (B_ - 1);
    const int tid = threadIdx.x;
    __shared__ float rd[V_];
    __shared__ float pf[PE_];
    if (tid < V_) rd[tid] = readv[(size_t)m * V_ + tid];
    if (tid < PE_) pf[tid] = prof[(size_t)b * PE_ + tid];
    __syncthreads();

    size_t base = (size_t)m * KF_;
    F[base + tid] = (_Float16)gruo[(size_t)m * H_ + tid];
    if (tid < V_) F[base + H_ + tid] = (_Float16)rd[tid];
    if (tid < PE_) {
        float a = attnP_b[tid];
        for (int k = 0; k < PE_; ++k) a += pf[k] * attnP_w[(size_t)k * PE_ + tid];
        for (int k = 0; k < V_; ++k) a += rd[k] * attnP_w[(size_t)(PE_ + k) * PE_ + tid];
        a = fmaxf(a, 0.0f);
        F[base + H_ + V_ + tid] = (_Float16)(pf[tid] * a);
    }
}

// ---------------------------------------------------------------------------
// Softmaxes
// ---------------------------------------------------------------------------
__global__ void k_softmax128(float* __restrict__ C)
{
    const int m = blockIdx.x;
    const size_t base = (size_t)m * S_;
    const int lane = threadIdx.x;
    float a = C[base + lane], b = C[base + 64 + lane];
    float mx = fmaxf(a, b);
    for (int o = 32; o; o >>= 1) mx = fmaxf(mx, __shfl_xor(mx, o));
    float e0 = __expf(a - mx), e1 = __expf(b - mx);
    float s = e0 + e1;
    for (int o = 32; o; o >>= 1) s += __shfl_xor(s, o);
    float inv = 1.0f / s;
    C[base + lane] = e0 * inv;
    C[base + 64 + lane] = e1 * inv;
}

// reads f16 logits, writes f32 probabilities to d_out
__global__ __launch_bounds__(256)
void k_softmax2000(const _Float16* __restrict__ L, float* __restrict__ C)
{
    const int m = blockIdx.x;
    const size_t base = (size_t)m * D_;
    const int tid = threadIdx.x;
    const int wid = tid >> 6, lane = tid & 63;
    __shared__ float red[4], red2[4];

    float v[8];
#pragma unroll
    for (int i = 0; i < 8; ++i) {
        int d = i * 256 + tid;
        v[i] = (d < D_) ? (float)L[base + d] : -1e30f;
    }
    float mx = v[0];
#pragma unroll
    for (int i = 1; i < 8; ++i) mx = fmaxf(mx, v[i]);
    for (int o = 32; o; o >>= 1) mx = fmaxf(mx, __shfl_xor(mx, o));
    if (lane == 0) red[wid] = mx;
    __syncthreads();
    mx = fmaxf(fmaxf(red[0], red[1]), fmaxf(red[2], red[3]));

    float sum = 0.0f;
#pragma unroll
    for (int i = 0; i < 8; ++i) { v[i] = __expf(v[i] - mx); sum += v[i]; }
    for (int o = 32; o; o >>= 1) sum += __shfl_xor(sum, o);
    if (lane == 0) red2[wid] = sum;
    __syncthreads();
    sum = red2[0] + red2[1] + red2[2] + red2[3];
    float inv = 1.0f / sum;
#pragma unroll
    for (int i = 0; i < 8; ++i) {
        int d = i * 256 + tid;
        if (d < D_) C[base + d] = v[i] * inv;
    }
}

// ---------------------------------------------------------------------------
// Launch
// ---------------------------------------------------------------------------
extern "C" void kernel_launch(void* const* d_in, const int* in_sizes, int n_in,
                              void* d_out, int out_size, void* d_ws, size_t ws_size,
                              hipStream_t stream)
{
    const float* X        = (const float*)d_in[0];
    const float* profiles = (const float*)d_in[1];
    const float* ini_embd = (const float*)d_in[2];
    const float* Wa_w     = (const float*)d_in[3];
    const float* Wa_b     = (const float*)d_in[4];
    const float* Ua_w     = (const float*)d_in[5];
    const float* gru_Wih  = (const float*)d_in[6];
    const float* gru_Whh  = (const float*)d_in[7];
    const float* gru_bih  = (const float*)d_in[8];
    const float* gru_bhh  = (const float*)d_in[9];
    const float* tranH_w  = (const float*)d_in[10];
    const float* tranH_b  = (const float*)d_in[11];
    const float* out_w    = (const float*)d_in[12];
    const float* out_b    = (const float*)d_in[13];
    const float* erase_w  = (const float*)d_in[14];
    const float* erase_b  = (const float*)d_in[15];
    const float* add_w    = (const float*)d_in[16];
    const float* add_b    = (const float*)d_in[17];
    const float* iniVam   = (const float*)d_in[18];
    const float* emP_w    = (const float*)d_in[19];
    const float* emP_b    = (const float*)d_in[20];
    const float* attnP_w  = (const float*)d_in[21];
    const float* attnP_b  = (const float*)d_in[22];
    const int* KMIds   = (const int*)d_in[23];
    const int* leaves1 = (const int*)d_in[24];
    const int* anc1    = (const int*)d_in[25];
    const int* leaves2 = (const int*)d_in[26];
    const int* anc2    = (const int*)d_in[27];
    const int* mapInfo = (const int*)d_in[28];
    const int* X_len   = (const int*)d_in[29];

    char* ws = (char*)d_ws;
    float* out = (float*)d_out;
    typedef __hip_bfloat16 bf16;

    // ---- workspace layout (bytes) ----
    // R0 (67,108,864): early PP+embG; then P4 [4][16384][256] f32; then Cg
    //   [16384][1024] f32; finally F16 @0 (14.7MB) + LG16 f16 logits
    //   @16,777,216 (65.5MB -> ends 82.3MB, overlapping dead gruo/R1).
    // R1 (16,777,216): gruo f32 (dead after build_final).
    // R2 (16,777,216): Xe/tran planes (dead after slot GEMM).
    // R3 (20,971,520): At planes; later slotw/readv.
    const size_t R0 = 0;
    const size_t R1 = 67108864;
    const size_t R2 = 83886080;
    const size_t R3 = 100663296;
    size_t P = 121634816;
    const size_t EMBHI = P; P += 1048576;
    const size_t EMBLO = P; P += 1048576;
    const size_t OWF  = P; P += 1835008;
    const size_t WGHI = P; P += 524288;
    const size_t WGLO = P; P += 524288;
    const size_t THHI = P; P += 163840;
    const size_t THLO = P; P += 163840;
    const size_t KMHI = P; P += 65536;
    const size_t KMLO = P; P += 65536;
    const size_t WRG  = P; P += 344064;
    const size_t WST  = P; P += 49152;
    const size_t PROF = P; P += 65536;
    const size_t BIAS = P; P += 4096;
    const size_t W2O  = P; P += 262144;

    float* PP      = (float*)(ws + R0);
    float* embG    = (float*)(ws + R0 + 12288000);
    float* P4      = (float*)(ws + R0);
    float* Cg      = (float*)(ws + R0);
    _Float16* F16  = (_Float16*)(ws + R0);
    _Float16* LG16 = (_Float16*)(ws + 16777216);
    float* gruo    = (float*)(ws + R1);
    bf16*  Xe_hi   = (bf16*)(ws + R2);
    bf16*  Xe_lo   = (bf16*)(ws + R2 + 8388608);
    bf16*  tran_hi = (bf16*)(ws + R2);
    bf16*  tran_lo = (bf16*)(ws + R2 + 8388608);
    bf16*  At_hi   = (bf16*)(ws + R3);
    bf16*  At_lo   = (bf16*)(ws + R3 + 10485760);
    float* slotw   = (float*)(ws + R3);
    float* readv   = (float*)(ws + R3 + 10485760);
    _Float16* EMBhi = (_Float16*)(ws + EMBHI);
    _Float16* EMBlo = (_Float16*)(ws + EMBLO);
    _Float16* OWf = (_Float16*)(ws + OWF);
    bf16*  WGhi = (bf16*)(ws + WGHI); bf16* WGlo = (bf16*)(ws + WGLO);
    bf16*  THhi = (bf16*)(ws + THHI); bf16* THlo = (bf16*)(ws + THLO);
    bf16*  KMhi = (bf16*)(ws + KMHI); bf16* KMlo = (bf16*)(ws + KMLO);
    unsigned int* Wrg = (unsigned int*)(ws + WRG);
    unsigned int* Wst = (unsigned int*)(ws + WST);
    float* prof  = (float*)(ws + PROF);
    float* biasG = (float*)(ws + BIAS);
    float* W2p   = (float*)(ws + W2O);

    // ---- weight packs ----
    k_pack_w2<<<(E_ * 2 * A_ + 255) / 256, 256, 0, stream>>>(Wa_w, W2p);
    k_wg_split<<<(1024 * 256 + 255) / 256, 256, 0, stream>>>(
        erase_w, add_w, gru_Wih, erase_b, add_b, gru_bih, WGhi, WGlo, biasG);
    k_tranHT_split<<<(256 * 320 + 255) / 256, 256, 0, stream>>>(tranH_w, THhi, THlo);
    k_outWT_f16<<<(2048 * 448 + 255) / 256, 256, 0, stream>>>(out_w, OWf);
    k_km_split<<<(S_ * E_ + 255) / 256, 256, 0, stream>>>(ini_embd, KMIds, KMhi, KMlo);
    k_wgru_pack<<<(768 * 128 + 255) / 256, 256, 0, stream>>>(gru_Whh, Wrg, Wst);
    k_prof<<<B_, PE_, 0, stream>>>(profiles, emP_w, emP_b, prof);

    // ---- ontology attention -> embedMat f16 planes ----
    {
        dim3 blk(16, 16);
        dim3 grid(4, (TN_ + 63) / 64);
        k_gemm<64, 64, 16, 4, 4><<<grid, blk, 0, stream>>>(ini_embd, W2p, PP, TN_, 256, E_);
    }
    k_group_embed<<<G1N_ + G2N_, 64, 0, stream>>>(PP, Wa_b, Ua_w, ini_embd,
                                                  leaves1, anc1, leaves2, anc2, embG);
    k_embMT_f16<<<(256 * 2048) / 256, 256, 0, stream>>>(embG, mapInfo, EMBhi, EMBlo);

    // ---- Xe = X @ embM : split-K f16 2-phase -> partials -> reduce+split ----
    k_mgemmX<<<SK_ * 256, 256, 0, stream>>>(X, EMBhi, EMBlo, P4);
    k_reduceX<<<(M_ * 256) / 256, 256, 0, stream>>>(P4, Xe_hi, Xe_lo);

    // ---- Cg = [era | gx] fused GEMM (bf16 3-phase, fp32-grade) ----
    k_mgemm3<2, false, 0, 3, 0><<<128 * 8, 256, 0, stream>>>(Xe_hi, Xe_lo, WGhi, WGlo,
        biasG, Cg, nullptr, nullptr, 256, 1024, 8);

    // ---- GRU scan v5 (gx from Cg) ----
    k_gru5<<<256, 768, 0, stream>>>(Cg, Wrg, (const uint4*)Wst, gru_bhh, X_len,
                                    gruo, At_hi, At_lo);
    k_fill_tp<<<(M_ * PE_) / 256, 256, 0, stream>>>(prof, At_hi, At_lo);

    // ---- tran = [gruo|prof] @ tranH + b ----
    k_mgemm3<0, false, 1, 3, 0><<<128 * 2, 256, 0, stream>>>(At_hi, At_lo, THhi, THlo,
        tranH_b, nullptr, tran_hi, tran_lo, 320, 256, 2);

    // ---- slot logits = tran @ KM^T ----
    k_mgemm3<0, false, 0, 3, 0><<<128 * 1, 256, 0, stream>>>(tran_hi, tran_lo, KMhi, KMlo,
        nullptr, slotw, nullptr, nullptr, 256, 128, 1);

    k_softmax128<<<M_, 64, 0, stream>>>(slotw);
    k_mem<<<B_, 256, 0, stream>>>(slotw, Cg, iniVam, readv);
    k_build_final<<<M_, 256, 0, stream>>>(gruo, readv, prof, attnP_w, attnP_b, F16);

    // ---- logits(f16) = F @ out_w + out_b ----
    k_mgemm3<0, false, 2, 1, 1><<<128 * 16, 256, 0, stream>>>(
        (const bf16*)F16, nullptr, (const bf16*)OWf, nullptr,
        out_b, nullptr, (bf16*)LG16, nullptr, 448, 2000, 16);

    k_softmax2000<<<M_, 256, 0, stream>>>(LG16, out);
}